// Round 16
// baseline (99.239 us; speedup 1.0000x reference)
//
#include <hip/hip_runtime.h>
#include <hip/hip_bf16.h>
#include <math.h>

#define DD 1024          // D (in == out features)
#define BT 8192          // B*N tokens
#define TWO_PI 6.28318530717958647692f

typedef float f32x4 __attribute__((ext_vector_type(4)));
typedef short bf16x8 __attribute__((ext_vector_type(8)));
typedef unsigned short u16x8 __attribute__((ext_vector_type(8)));
typedef unsigned short u16x4 __attribute__((ext_vector_type(4)));
typedef const __attribute__((address_space(1))) void g_void;
typedef __attribute__((address_space(3))) void l_void;

__device__ __forceinline__ unsigned short f2bf(float f) {
  unsigned int u = __float_as_uint(f);
  unsigned int r = (u + 0x7FFFu + ((u >> 16) & 1u)) >> 16;   // RNE
  return (unsigned short)r;
}

// ---------------------------------------------------------------------------
// build_G: G[k,m] = sum_o W[k,o] e^{+2pi i o m/D}. One block per k-row;
// coalesced row reads (sparsity is per-row), scan compaction, twiddle table.
// ---------------------------------------------------------------------------
__global__ __launch_bounds__(256) void build_G_kernel(
    const float* __restrict__ Wr, const float* __restrict__ Wi,
    float2* __restrict__ Gf) {
  __shared__ float2 tw[DD];
  __shared__ int    oidx[64];
  __shared__ float2 wval[64];
  __shared__ int    sc[256];
  const int k = blockIdx.x, tid = threadIdx.x;

  for (int j = tid; j < DD; j += 256) {
    float s, c;
    sincosf((TWO_PI / DD) * (float)j, &s, &c);
    tw[j] = make_float2(c, s);
  }
  int cnt = 0;
  float2 wl[4];
  int    ol[4];
#pragma unroll
  for (int q = 0; q < 4; q++) {
    int o = tid + q * 256;
    float wr = Wr[(size_t)k * DD + o];
    float wi = Wi[(size_t)k * DD + o];
    if (wr != 0.f || wi != 0.f) { wl[cnt] = make_float2(wr, wi); ol[cnt] = o; cnt++; }
  }
  sc[tid] = cnt;
  __syncthreads();
#pragma unroll
  for (int dstep = 1; dstep < 256; dstep <<= 1) {
    int v = (tid >= dstep) ? sc[tid - dstep] : 0;
    __syncthreads();
    sc[tid] += v;
    __syncthreads();
  }
  int p = sc[tid] - cnt;
  for (int q = 0; q < cnt; q++) { oidx[p + q] = ol[q]; wval[p + q] = wl[q]; }
  __syncthreads();
  const int nnz = sc[255];
  for (int m = tid; m < DD; m += 256) {
    float re = 0.f, im = 0.f;
    for (int j = 0; j < nnz; j++) {
      int    o  = oidx[j];
      float2 w  = wval[j];
      float2 cs = tw[(o * m) & (DD - 1)];     // e^{+i th} = (c, s)
      re += w.x * cs.x - w.y * cs.y;
      im += w.x * cs.y + w.y * cs.x;
    }
    Gf[(size_t)k * DD + m] = make_float2(re, im);
  }
}

// ---------------------------------------------------------------------------
// transpose_G: Gt[m][k] = bf16(Re Gf[k][m]); Gt[m][1024+k] = bf16(Im).
// ---------------------------------------------------------------------------
__global__ __launch_bounds__(256) void transpose_G_kernel(
    const float2* __restrict__ Gf, unsigned short* __restrict__ Gt) {
  __shared__ float2 tile[64][65];
  const int k0 = blockIdx.x * 64, m0 = blockIdx.y * 64;
  for (int q = threadIdx.x; q < 64 * 64; q += 256) {
    int r = q >> 6, c = q & 63;                 // r: k, c: m
    tile[r][c] = Gf[(size_t)(k0 + r) * DD + m0 + c];
  }
  __syncthreads();
  for (int q = threadIdx.x; q < 64 * 64; q += 256) {
    int r = q >> 6, c = q & 63;                 // r: m, c: k
    float2 v = tile[c][r];
    Gt[(size_t)(m0 + r) * 2048 + k0 + c]        = f2bf(v.x);
    Gt[(size_t)(m0 + r) * 2048 + 1024 + k0 + c] = f2bf(v.y);
  }
}

// ---------------------------------------------------------------------------
// build_M + convert_x fused launch (independent jobs, one dispatch):
// blocks [0,128): P_z[m][d] = sum_{K in z-chunk} Gt[m][K] * B(d,K)
//   (B generated in-register; A via global_load_lds; 128x128, BK=32,
//    split-K x2, kLen=1024). Compute-bound; runs on CUs freed as the
//    convert blocks drain.
// blocks [128,4224): Xb = bf16(x) — memory-bound, sets the kernel floor.
// NOTE (R14 lesson): no __threadfence/atomic handoff — device-scope fences
// force per-XCD L2 writeback on this arch (cost >> a launch gap).
// ---------------------------------------------------------------------------
__global__ __launch_bounds__(256) void build_M_convert_kernel(
    const unsigned short* __restrict__ Gt,   // (1024 x 2048) bf16, m-major
    float* __restrict__ P,
    const float* __restrict__ X, unsigned short* __restrict__ Xb) {
  __shared__ __align__(16) unsigned short Asm[128 * 32];
  __shared__ __align__(16) unsigned short Bsm[128 * 32];
  const int tid = threadIdx.x;

  if (blockIdx.x >= 128) {                 // ---- convert_x part ----
    size_t i = (size_t)(blockIdx.x - 128) * 256 + tid;   // chunk of 8
    const float4* p = (const float4*)(X + i * 8);
    float4 a = p[0], c = p[1];
    u16x8 v;
    v[0] = f2bf(a.x); v[1] = f2bf(a.y); v[2] = f2bf(a.z); v[3] = f2bf(a.w);
    v[4] = f2bf(c.x); v[5] = f2bf(c.y); v[6] = f2bf(c.z); v[7] = f2bf(c.w);
    *(u16x8*)(Xb + i * 8) = v;
    return;
  }

  // ---- build_M part: 128 = (d-tile 8) x (m-tile 8) x (z 2) ----
  const int wave = tid >> 6, lane = tid & 63;
  const int wr = wave >> 1, wc = wave & 1;
  const int col0 = (blockIdx.x & 7) * 128;         // d
  const int row0 = ((blockIdx.x >> 3) & 7) * 128;  // m
  const int bz   = blockIdx.x >> 6;                // k-chunk (0 or 1)
  const int kBeg = bz * 1024;

  f32x4 acc[4][4] = {};

  for (int k0 = kBeg; k0 < kBeg + 1024; k0 += 32) {
    __syncthreads();
#pragma unroll
    for (int is = 0; is < 2; is++) {     // A = Gt rows (m-major)
      int e = is * 256 + tid;
      int r = e >> 2, c = (e & 3) * 8;
      const unsigned short* ga = Gt + (size_t)(row0 + r) * 2048 + k0 + c;
      __builtin_amdgcn_global_load_lds((g_void*)ga,
          (l_void*)(Asm + is * 2048 + wave * 512), 16, 0, 0);
    }
#pragma unroll
    for (int is = 0; is < 2; is++) {     // B = generated twiddles
      int e = is * 256 + tid;
      int r = e >> 2, c = (e & 3) * 8;
      int d = col0 + r;
      u16x8 v;
#pragma unroll
      for (int q = 0; q < 8; q++) {
        int K   = k0 + c + q;
        int idx = (K * d) & (DD - 1);
        float s, cc;
        __sincosf((TWO_PI / DD) * (float)idx, &s, &cc);
        v[q] = f2bf((K < DD) ? cc : s);
      }
      *(u16x8*)(Bsm + e * 8) = v;
    }
    __syncthreads();

    bf16x8 af[4], bfr[4];
#pragma unroll
    for (int i = 0; i < 4; i++) {
      int ra = wr * 64 + i * 16 + (lane & 15);
      af[i]  = *(const bf16x8*)&Asm[ra * 32 + (lane >> 4) * 8];
      int rb = wc * 64 + i * 16 + (lane & 15);
      bfr[i] = *(const bf16x8*)&Bsm[rb * 32 + (lane >> 4) * 8];
    }
#pragma unroll
    for (int i = 0; i < 4; i++)
#pragma unroll
      for (int j = 0; j < 4; j++)
        acc[i][j] = __builtin_amdgcn_mfma_f32_16x16x32_bf16(af[i], bfr[j], acc[i][j], 0, 0, 0);
  }

  const int crow0 = row0 + wr * 64;
  const int ccol0 = col0 + wc * 64;
  float* O = P + (size_t)bz * DD * DD;
#pragma unroll
  for (int i = 0; i < 4; i++)
#pragma unroll
    for (int j = 0; j < 4; j++) {
      int cc = ccol0 + j * 16 + (lane & 15);
#pragma unroll
      for (int v = 0; v < 4; v++) {
        int rr = crow0 + i * 16 + (lane >> 4) * 4 + v;
        O[(size_t)rr * DD + cc] = acc[i][j][v];
      }
    }
}

// ---------------------------------------------------------------------------
// reduce_M: Mb[i] = bf16( (P0[i]+P1[i]) / D ),  x4 vectorized, 2 partials.
// ---------------------------------------------------------------------------
__global__ __launch_bounds__(256) void reduce_M_kernel(
    const float* __restrict__ P, unsigned short* __restrict__ Mb) {
  const size_t NE = (size_t)DD * DD;
  size_t i = ((size_t)blockIdx.x * 256 + threadIdx.x) * 4;
  float4 s = *(const float4*)(P + i);
  float4 p = *(const float4*)(P + NE + i);
  s.x += p.x; s.y += p.y; s.z += p.z; s.w += p.w;
  const float inv = 1.0f / (float)DD;
  u16x4 v;
  v[0] = f2bf(s.x * inv); v[1] = f2bf(s.y * inv);
  v[2] = f2bf(s.z * inv); v[3] = f2bf(s.w * inv);
  *(u16x4*)(Mb + i) = v;
}

// ---------------------------------------------------------------------------
// gemm_y (R12/R13-proven best): 128x128 tile, 4 waves, BK=32, gload_lds w16,
// 2-barrier loop + chunked XCD swizzle (xcd = L&7 owns an 8x8 tile square).
// Plain Y stores (R15's NT-Y was neutral-to-negative — reverted).
// ---------------------------------------------------------------------------
__global__ __launch_bounds__(256) void gemm_y_kernel(
    const unsigned short* __restrict__ Xb,   // (8192 x 1024) bf16
    const unsigned short* __restrict__ Mb,   // (1024 x 1024) bf16
    const float* __restrict__ bias,
    float* __restrict__ Y) {
  __shared__ __align__(16) unsigned short Asm[128 * 32];
  __shared__ __align__(16) unsigned short Bsm[128 * 32];
  const int tid  = threadIdx.x;
  const int wave = tid >> 6, lane = tid & 63;
  const int wr = wave >> 1, wc = wave & 1;

  const int L  = blockIdx.x;
  const int w  = (L & 7) * 64 + (L >> 3);
  const int row0 = (w >> 3) * 128;
  const int col0 = (w & 7) * 128;

  f32x4 acc[4][4] = {};

  for (int k0 = 0; k0 < DD; k0 += 32) {
    __syncthreads();
#pragma unroll
    for (int is = 0; is < 2; is++) {
      int e = is * 256 + tid;
      int r = e >> 2, c = (e & 3) * 8;
      const unsigned short* ga = Xb + (size_t)(row0 + r) * DD + k0 + c;
      const unsigned short* gb = Mb + (size_t)(col0 + r) * DD + k0 + c;
      __builtin_amdgcn_global_load_lds((g_void*)ga,
          (l_void*)(Asm + is * 2048 + wave * 512), 16, 0, 0);
      __builtin_amdgcn_global_load_lds((g_void*)gb,
          (l_void*)(Bsm + is * 2048 + wave * 512), 16, 0, 0);
    }
    __syncthreads();

    bf16x8 af[4], bfr[4];
#pragma unroll
    for (int i = 0; i < 4; i++) {
      int ra = wr * 64 + i * 16 + (lane & 15);
      af[i]  = *(const bf16x8*)&Asm[ra * 32 + (lane >> 4) * 8];
      int rb = wc * 64 + i * 16 + (lane & 15);
      bfr[i] = *(const bf16x8*)&Bsm[rb * 32 + (lane >> 4) * 8];
    }
#pragma unroll
    for (int i = 0; i < 4; i++)
#pragma unroll
      for (int j = 0; j < 4; j++)
        acc[i][j] = __builtin_amdgcn_mfma_f32_16x16x32_bf16(af[i], bfr[j], acc[i][j], 0, 0, 0);
  }

  const int crow0 = row0 + wr * 64;
  const int ccol0 = col0 + wc * 64;
  float bv[4];
#pragma unroll
  for (int j = 0; j < 4; j++)
    bv[j] = bias[ccol0 + j * 16 + (lane & 15)];
#pragma unroll
  for (int i = 0; i < 4; i++)
#pragma unroll
    for (int j = 0; j < 4; j++) {
      int cc = ccol0 + j * 16 + (lane & 15);
#pragma unroll
      for (int v = 0; v < 4; v++) {
        int rr = crow0 + i * 16 + (lane >> 4) * 4 + v;
        Y[(size_t)rr * DD + cc] = acc[i][j][v] + bv[j];
      }
    }
}

// ---------------------------------------------------------------------------
extern "C" void kernel_launch(void* const* d_in, const int* in_sizes, int n_in,
                              void* d_out, int out_size, void* d_ws, size_t ws_size,
                              hipStream_t stream) {
  const float* x    = (const float*)d_in[0];
  const float* wrp  = (const float*)d_in[1];
  const float* wip  = (const float*)d_in[2];
  const float* bias = (const float*)d_in[3];
  float*       y    = (float*)d_out;

  char* ws = (char*)d_ws;
  const size_t MB = 1024 * 1024;
  float2*         Gf = (float2*)(ws + 0);                // 8 MB  [k][m]
  unsigned short* Gt = (unsigned short*)(ws + 8 * MB);   // 4 MB  [m][2048]
  unsigned short* Mb = (unsigned short*)(ws + 12 * MB);  // 2 MB  [m][d]
  float*          P  = (float*)(ws + 16 * MB);           // 8 MB (2 partials)
  unsigned short* Xb = (unsigned short*)(ws + 32 * MB);  // 16 MB

  build_G_kernel<<<DD, 256, 0, stream>>>(wrp, wip, Gf);
  transpose_G_kernel<<<dim3(16, 16), 256, 0, stream>>>(Gf, Gt);
  // P (128 MFMA blocks, split-K x2) + Xb = bf16(x) (4096 blocks)
  build_M_convert_kernel<<<4224, 256, 0, stream>>>(Gt, P, x, Xb);
  reduce_M_kernel<<<DD, 256, 0, stream>>>(P, Mb);
  // Y = Xb . Mb^T + bias   (XCD-chunk swizzled 1-D grid)
  gemm_y_kernel<<<512, 256, 0, stream>>>(Xb, Mb, bias, y);
}

// Round 17
// 87.860 us; speedup vs baseline: 1.1295x; 1.1295x over previous
//
#include <hip/hip_runtime.h>
#include <hip/hip_bf16.h>
#include <math.h>

#define DD 1024          // D (in == out features)
#define BT 8192          // B*N tokens
#define TWO_PI 6.28318530717958647692f

typedef float f32x4 __attribute__((ext_vector_type(4)));
typedef short bf16x8 __attribute__((ext_vector_type(8)));
typedef unsigned short u16x8 __attribute__((ext_vector_type(8)));
typedef unsigned short u16x4 __attribute__((ext_vector_type(4)));
typedef const __attribute__((address_space(1))) void g_void;
typedef __attribute__((address_space(3))) void l_void;

__device__ __forceinline__ unsigned short f2bf(float f) {
  unsigned int u = __float_as_uint(f);
  unsigned int r = (u + 0x7FFFu + ((u >> 16) & 1u)) >> 16;   // RNE
  return (unsigned short)r;
}

// ---------------------------------------------------------------------------
// build_G: G[k,m] = sum_o W[k,o] e^{+2pi i o m/D}. One block per k-row;
// coalesced row reads (sparsity is per-row), scan compaction, twiddle table.
// ---------------------------------------------------------------------------
__global__ __launch_bounds__(256) void build_G_kernel(
    const float* __restrict__ Wr, const float* __restrict__ Wi,
    float2* __restrict__ Gf) {
  __shared__ float2 tw[DD];
  __shared__ int    oidx[64];
  __shared__ float2 wval[64];
  __shared__ int    sc[256];
  const int k = blockIdx.x, tid = threadIdx.x;

  for (int j = tid; j < DD; j += 256) {
    float s, c;
    sincosf((TWO_PI / DD) * (float)j, &s, &c);
    tw[j] = make_float2(c, s);
  }
  int cnt = 0;
  float2 wl[4];
  int    ol[4];
#pragma unroll
  for (int q = 0; q < 4; q++) {
    int o = tid + q * 256;
    float wr = Wr[(size_t)k * DD + o];
    float wi = Wi[(size_t)k * DD + o];
    if (wr != 0.f || wi != 0.f) { wl[cnt] = make_float2(wr, wi); ol[cnt] = o; cnt++; }
  }
  sc[tid] = cnt;
  __syncthreads();
#pragma unroll
  for (int dstep = 1; dstep < 256; dstep <<= 1) {
    int v = (tid >= dstep) ? sc[tid - dstep] : 0;
    __syncthreads();
    sc[tid] += v;
    __syncthreads();
  }
  int p = sc[tid] - cnt;
  for (int q = 0; q < cnt; q++) { oidx[p + q] = ol[q]; wval[p + q] = wl[q]; }
  __syncthreads();
  const int nnz = sc[255];
  for (int m = tid; m < DD; m += 256) {
    float re = 0.f, im = 0.f;
    for (int j = 0; j < nnz; j++) {
      int    o  = oidx[j];
      float2 w  = wval[j];
      float2 cs = tw[(o * m) & (DD - 1)];     // e^{+i th} = (c, s)
      re += w.x * cs.x - w.y * cs.y;
      im += w.x * cs.y + w.y * cs.x;
    }
    Gf[(size_t)k * DD + m] = make_float2(re, im);
  }
}

// ---------------------------------------------------------------------------
// transpose_G: Gt[m][k] = bf16(Re Gf[k][m]); Gt[m][1024+k] = bf16(Im).
// ---------------------------------------------------------------------------
__global__ __launch_bounds__(256) void transpose_G_kernel(
    const float2* __restrict__ Gf, unsigned short* __restrict__ Gt) {
  __shared__ float2 tile[64][65];
  const int k0 = blockIdx.x * 64, m0 = blockIdx.y * 64;
  for (int q = threadIdx.x; q < 64 * 64; q += 256) {
    int r = q >> 6, c = q & 63;                 // r: k, c: m
    tile[r][c] = Gf[(size_t)(k0 + r) * DD + m0 + c];
  }
  __syncthreads();
  for (int q = threadIdx.x; q < 64 * 64; q += 256) {
    int r = q >> 6, c = q & 63;                 // r: m, c: k
    float2 v = tile[c][r];
    Gt[(size_t)(m0 + r) * 2048 + k0 + c]        = f2bf(v.x);
    Gt[(size_t)(m0 + r) * 2048 + 1024 + k0 + c] = f2bf(v.y);
  }
}

// ---------------------------------------------------------------------------
// build_M + convert_x fused launch (independent jobs, one dispatch):
// blocks [0,256): P_z[m][d] = sum_{K in z-chunk} Gt[m][K] * B(d,K)
//   (B generated in-register; A via global_load_lds; 128x128, BK=32,
//    split-K x4, kLen=512 — R16 showed x2 regresses: 1 block/CU MFMA tail
//    runs unoverlapped). Compute-bound.
// blocks [256,4352): Xb = bf16(x) — streams under the MFMA compute.
// NOTE (R14 lesson): no __threadfence/atomic handoff — device-scope fences
// force per-XCD L2 writeback on this arch (cost >> a launch gap).
// ---------------------------------------------------------------------------
__global__ __launch_bounds__(256) void build_M_convert_kernel(
    const unsigned short* __restrict__ Gt,   // (1024 x 2048) bf16, m-major
    float* __restrict__ P,
    const float* __restrict__ X, unsigned short* __restrict__ Xb) {
  __shared__ __align__(16) unsigned short Asm[128 * 32];
  __shared__ __align__(16) unsigned short Bsm[128 * 32];
  const int tid = threadIdx.x;

  if (blockIdx.x >= 256) {                 // ---- convert_x part ----
    size_t i = (size_t)(blockIdx.x - 256) * 256 + tid;   // chunk of 8
    const float4* p = (const float4*)(X + i * 8);
    float4 a = p[0], c = p[1];
    u16x8 v;
    v[0] = f2bf(a.x); v[1] = f2bf(a.y); v[2] = f2bf(a.z); v[3] = f2bf(a.w);
    v[4] = f2bf(c.x); v[5] = f2bf(c.y); v[6] = f2bf(c.z); v[7] = f2bf(c.w);
    *(u16x8*)(Xb + i * 8) = v;
    return;
  }

  // ---- build_M part: 256 = (d-tile 8) x (m-tile 8) x (z 4) ----
  const int wave = tid >> 6, lane = tid & 63;
  const int wr = wave >> 1, wc = wave & 1;
  const int col0 = (blockIdx.x & 7) * 128;         // d
  const int row0 = ((blockIdx.x >> 3) & 7) * 128;  // m
  const int bz   = blockIdx.x >> 6;                // k-chunk
  const int kBeg = bz * 512;

  f32x4 acc[4][4] = {};

  for (int k0 = kBeg; k0 < kBeg + 512; k0 += 32) {
    __syncthreads();
#pragma unroll
    for (int is = 0; is < 2; is++) {     // A = Gt rows (m-major)
      int e = is * 256 + tid;
      int r = e >> 2, c = (e & 3) * 8;
      const unsigned short* ga = Gt + (size_t)(row0 + r) * 2048 + k0 + c;
      __builtin_amdgcn_global_load_lds((g_void*)ga,
          (l_void*)(Asm + is * 2048 + wave * 512), 16, 0, 0);
    }
#pragma unroll
    for (int is = 0; is < 2; is++) {     // B = generated twiddles
      int e = is * 256 + tid;
      int r = e >> 2, c = (e & 3) * 8;
      int d = col0 + r;
      u16x8 v;
#pragma unroll
      for (int q = 0; q < 8; q++) {
        int K   = k0 + c + q;
        int idx = (K * d) & (DD - 1);
        float s, cc;
        __sincosf((TWO_PI / DD) * (float)idx, &s, &cc);
        v[q] = f2bf((K < DD) ? cc : s);
      }
      *(u16x8*)(Bsm + e * 8) = v;
    }
    __syncthreads();

    bf16x8 af[4], bfr[4];
#pragma unroll
    for (int i = 0; i < 4; i++) {
      int ra = wr * 64 + i * 16 + (lane & 15);
      af[i]  = *(const bf16x8*)&Asm[ra * 32 + (lane >> 4) * 8];
      int rb = wc * 64 + i * 16 + (lane & 15);
      bfr[i] = *(const bf16x8*)&Bsm[rb * 32 + (lane >> 4) * 8];
    }
#pragma unroll
    for (int i = 0; i < 4; i++)
#pragma unroll
      for (int j = 0; j < 4; j++)
        acc[i][j] = __builtin_amdgcn_mfma_f32_16x16x32_bf16(af[i], bfr[j], acc[i][j], 0, 0, 0);
  }

  const int crow0 = row0 + wr * 64;
  const int ccol0 = col0 + wc * 64;
  float* O = P + (size_t)bz * DD * DD;
#pragma unroll
  for (int i = 0; i < 4; i++)
#pragma unroll
    for (int j = 0; j < 4; j++) {
      int cc = ccol0 + j * 16 + (lane & 15);
#pragma unroll
      for (int v = 0; v < 4; v++) {
        int rr = crow0 + i * 16 + (lane >> 4) * 4 + v;
        O[(size_t)rr * DD + cc] = acc[i][j][v];
      }
    }
}

// ---------------------------------------------------------------------------
// reduce_M: Mb[i] = bf16( sum_z P_z[i] / D ),  x4 vectorized, 4 partials.
// ---------------------------------------------------------------------------
__global__ __launch_bounds__(256) void reduce_M_kernel(
    const float* __restrict__ P, unsigned short* __restrict__ Mb) {
  const size_t NE = (size_t)DD * DD;
  size_t i = ((size_t)blockIdx.x * 256 + threadIdx.x) * 4;
  float4 s = *(const float4*)(P + i);
#pragma unroll
  for (int z = 1; z < 4; z++) {
    float4 p = *(const float4*)(P + z * NE + i);
    s.x += p.x; s.y += p.y; s.z += p.z; s.w += p.w;
  }
  const float inv = 1.0f / (float)DD;
  u16x4 v;
  v[0] = f2bf(s.x * inv); v[1] = f2bf(s.y * inv);
  v[2] = f2bf(s.z * inv); v[3] = f2bf(s.w * inv);
  *(u16x4*)(Mb + i) = v;
}

// ---------------------------------------------------------------------------
// gemm_y (R12/R13-proven best): 128x128 tile, 4 waves, BK=32, gload_lds w16,
// 2-barrier loop + chunked XCD swizzle (xcd = L&7 owns an 8x8 tile square).
// Plain Y stores (R15's NT-Y was neutral — reverted).
// ---------------------------------------------------------------------------
__global__ __launch_bounds__(256) void gemm_y_kernel(
    const unsigned short* __restrict__ Xb,   // (8192 x 1024) bf16
    const unsigned short* __restrict__ Mb,   // (1024 x 1024) bf16
    const float* __restrict__ bias,
    float* __restrict__ Y) {
  __shared__ __align__(16) unsigned short Asm[128 * 32];
  __shared__ __align__(16) unsigned short Bsm[128 * 32];
  const int tid  = threadIdx.x;
  const int wave = tid >> 6, lane = tid & 63;
  const int wr = wave >> 1, wc = wave & 1;

  const int L  = blockIdx.x;
  const int w  = (L & 7) * 64 + (L >> 3);
  const int row0 = (w >> 3) * 128;
  const int col0 = (w & 7) * 128;

  f32x4 acc[4][4] = {};

  for (int k0 = 0; k0 < DD; k0 += 32) {
    __syncthreads();
#pragma unroll
    for (int is = 0; is < 2; is++) {
      int e = is * 256 + tid;
      int r = e >> 2, c = (e & 3) * 8;
      const unsigned short* ga = Xb + (size_t)(row0 + r) * DD + k0 + c;
      const unsigned short* gb = Mb + (size_t)(col0 + r) * DD + k0 + c;
      __builtin_amdgcn_global_load_lds((g_void*)ga,
          (l_void*)(Asm + is * 2048 + wave * 512), 16, 0, 0);
      __builtin_amdgcn_global_load_lds((g_void*)gb,
          (l_void*)(Bsm + is * 2048 + wave * 512), 16, 0, 0);
    }
    __syncthreads();

    bf16x8 af[4], bfr[4];
#pragma unroll
    for (int i = 0; i < 4; i++) {
      int ra = wr * 64 + i * 16 + (lane & 15);
      af[i]  = *(const bf16x8*)&Asm[ra * 32 + (lane >> 4) * 8];
      int rb = wc * 64 + i * 16 + (lane & 15);
      bfr[i] = *(const bf16x8*)&Bsm[rb * 32 + (lane >> 4) * 8];
    }
#pragma unroll
    for (int i = 0; i < 4; i++)
#pragma unroll
      for (int j = 0; j < 4; j++)
        acc[i][j] = __builtin_amdgcn_mfma_f32_16x16x32_bf16(af[i], bfr[j], acc[i][j], 0, 0, 0);
  }

  const int crow0 = row0 + wr * 64;
  const int ccol0 = col0 + wc * 64;
  float bv[4];
#pragma unroll
  for (int j = 0; j < 4; j++)
    bv[j] = bias[ccol0 + j * 16 + (lane & 15)];
#pragma unroll
  for (int i = 0; i < 4; i++)
#pragma unroll
    for (int j = 0; j < 4; j++) {
      int cc = ccol0 + j * 16 + (lane & 15);
#pragma unroll
      for (int v = 0; v < 4; v++) {
        int rr = crow0 + i * 16 + (lane >> 4) * 4 + v;
        Y[(size_t)rr * DD + cc] = acc[i][j][v] + bv[j];
      }
    }
}

// ---------------------------------------------------------------------------
extern "C" void kernel_launch(void* const* d_in, const int* in_sizes, int n_in,
                              void* d_out, int out_size, void* d_ws, size_t ws_size,
                              hipStream_t stream) {
  const float* x    = (const float*)d_in[0];
  const float* wrp  = (const float*)d_in[1];
  const float* wip  = (const float*)d_in[2];
  const float* bias = (const float*)d_in[3];
  float*       y    = (float*)d_out;

  char* ws = (char*)d_ws;
  const size_t MB = 1024 * 1024;
  float2*         Gf = (float2*)(ws + 0);                // 8 MB  [k][m]
  unsigned short* Gt = (unsigned short*)(ws + 8 * MB);   // 4 MB  [m][2048]
  unsigned short* Mb = (unsigned short*)(ws + 12 * MB);  // 2 MB  [m][d]
  float*          P  = (float*)(ws + 16 * MB);           // 16 MB (4 partials)
  unsigned short* Xb = (unsigned short*)(ws + 32 * MB);  // 16 MB

  build_G_kernel<<<DD, 256, 0, stream>>>(wrp, wip, Gf);
  transpose_G_kernel<<<dim3(16, 16), 256, 0, stream>>>(Gf, Gt);
  // P (256 MFMA blocks, split-K x4) + Xb = bf16(x) (4096 blocks)
  build_M_convert_kernel<<<4352, 256, 0, stream>>>(Gt, P, x, Xb);
  reduce_M_kernel<<<DD, 256, 0, stream>>>(P, Mb);
  // Y = Xb . Mb^T + bias   (XCD-chunk swizzled 1-D grid)
  gemm_y_kernel<<<512, 256, 0, stream>>>(Xb, Mb, bias, y);
}